// Round 1
// baseline (1756.741 us; speedup 1.0000x reference)
//
#include <hip/hip_runtime.h>

// Problem constants: inputs [16,256,64,64] f32, embedding [2048,256] f32
#define NROWS   65536      // 16*64*64 flattened vectors
#define KCODES  2048
#define DDIM    256
#define HWSZ    4096       // 64*64

// Output layout (float element offsets into d_out), reference return order:
//   loss(1), quantized[16,256,64,64](16777216), perplexity(1), encodings[65536,2048](134217728)
#define OUT_LOSS 0
#define OUT_Q    1
#define OUT_PERP 16777217
#define OUT_ENC  16777218

// Scratch carved from the encodings output region (overwritten last by k_onehot):
#define SCR_PART (OUT_ENC)                // float2 part[65536][16]  -> 4,194,304 floats
#define SCR_ET   (OUT_ENC + 4194304)     // float ET[256][2048]     -> 524,288 floats
#define SCR_E2   (OUT_ENC + 4718592)     // float e2[2048]
#define SCR_CNT  (OUT_ENC + 4720640)     // int counts[2048]
#define SCR_SUM  (OUT_ENC + 4722688)     // float sumsq[1]

// ---------------------------------------------------------------- transpose
__launch_bounds__(256)
__global__ void k_transpose(const float* __restrict__ emb, float* __restrict__ ET) {
    __shared__ float tile[32][33];
    const int kb = blockIdx.x * 32;   // code tile base (2048/32 = 64)
    const int db = blockIdx.y * 32;   // dim tile base  (256/32  = 8)
    const int tx = threadIdx.x & 31;
    const int ty = threadIdx.x >> 5;  // 0..7
#pragma unroll
    for (int i = 0; i < 32; i += 8)
        tile[ty + i][tx] = emb[(kb + ty + i) * DDIM + db + tx];
    __syncthreads();
#pragma unroll
    for (int i = 0; i < 32; i += 8)
        ET[(db + ty + i) * KCODES + kb + tx] = tile[tx][ty + i];
}

// ---------------------------------------------------------------- ||e||^2
__launch_bounds__(256)
__global__ void k_e2(const float* __restrict__ emb, float* __restrict__ e2) {
    const int wave = threadIdx.x >> 6;
    const int lane = threadIdx.x & 63;
    const int k = blockIdx.x * 4 + wave;           // grid 512 -> k in [0,2048)
    const float4 v = *(const float4*)(emb + k * DDIM + lane * 4);
    float s = v.x * v.x + v.y * v.y + v.z * v.z + v.w * v.w;
#pragma unroll
    for (int off = 32; off >= 1; off >>= 1) s += __shfl_down(s, off);
    if (lane == 0) e2[k] = s;
}

// ---------------------------------------------------------------- main: partial argmin per (rowblock, coltile)
// dist(n,k) = ||e_k||^2 - 2 * x_n . e_k   (row-constant ||x||^2 dropped: argmin-invariant)
__launch_bounds__(256)
__global__ void k_argmin_part(const float* __restrict__ inp, const float* __restrict__ ET,
                              const float* __restrict__ e2, float2* __restrict__ part) {
    __shared__ float Xs[8][128];
    __shared__ float Es[8][128];
    __shared__ float redv[128][16];
    __shared__ int   redi[128][16];

    const int ct  = blockIdx.x;          // coltile 0..15  (128 codes each)
    const int rb  = blockIdx.y;          // rowblock 0..511 (128 rows each)
    const int n0  = rb * 128;
    const int b   = n0 >> 12;            // image index (128 | 4096 so no straddle)
    const int hw0 = n0 & (HWSZ - 1);
    const int tid  = threadIdx.x;
    const int tx   = tid & 15, ty = tid >> 4;
    const int r0   = ty * 8, c0 = tx * 8;
    const int dloc = tid >> 5;           // 0..7
    const int rseg = (tid & 31) << 2;    // 0..124

    float acc[8][8];
#pragma unroll
    for (int i = 0; i < 8; ++i)
#pragma unroll
        for (int j = 0; j < 8; ++j) acc[i][j] = 0.0f;

    // x[n,d] = inputs[b*1048576 + d*4096 + (n&4095)]  -> coalesced along rows
    const float* gx = inp + b * 1048576 + hw0 + rseg;
    const float* ge = ET + ct * 128 + rseg;

    for (int kc = 0; kc < 32; ++kc) {
        const int d = kc * 8 + dloc;
        const float4 xv = *(const float4*)(gx + d * 4096);
        const float4 ev = *(const float4*)(ge + d * 2048);
        __syncthreads();
        *(float4*)&Xs[dloc][rseg] = xv;
        *(float4*)&Es[dloc][rseg] = ev;
        __syncthreads();
#pragma unroll
        for (int kd = 0; kd < 8; ++kd) {
            const float4 a0 = *(const float4*)&Xs[kd][r0];
            const float4 a1 = *(const float4*)&Xs[kd][r0 + 4];
            const float4 b0 = *(const float4*)&Es[kd][c0];
            const float4 b1 = *(const float4*)&Es[kd][c0 + 4];
            const float av[8]  = {a0.x, a0.y, a0.z, a0.w, a1.x, a1.y, a1.z, a1.w};
            const float bvv[8] = {b0.x, b0.y, b0.z, b0.w, b1.x, b1.y, b1.z, b1.w};
#pragma unroll
            for (int i = 0; i < 8; ++i)
#pragma unroll
                for (int j = 0; j < 8; ++j)
                    acc[i][j] = fmaf(av[i], bvv[j], acc[i][j]);
        }
    }

    // per-thread argmin over its 8 cols for each of its 8 rows (ascending col -> strict <)
    float e2v[8];
#pragma unroll
    for (int j = 0; j < 8; ++j) e2v[j] = e2[ct * 128 + c0 + j];

    float bestv[8]; int besti[8];
#pragma unroll
    for (int i = 0; i < 8; ++i) {
        float bv = 3.402823466e38f; int bi = 0;
#pragma unroll
        for (int j = 0; j < 8; ++j) {
            const float dist = fmaf(-2.0f, acc[i][j], e2v[j]);
            if (dist < bv) { bv = dist; bi = ct * 128 + c0 + j; }
        }
        bestv[i] = bv; besti[i] = bi;
    }

    __syncthreads();
#pragma unroll
    for (int i = 0; i < 8; ++i) { redv[r0 + i][tx] = bestv[i]; redi[r0 + i][tx] = besti[i]; }
    __syncthreads();

    if (tid < 128) {
        float bv = redv[tid][0]; int bi = redi[tid][0];
#pragma unroll
        for (int t = 1; t < 16; ++t) {
            const float v = redv[tid][t]; const int ii = redi[tid][t];
            if (v < bv || (v == bv && ii < bi)) { bv = v; bi = ii; }
        }
        part[(n0 + tid) * 16 + ct] = make_float2(bv, __int_as_float(bi));
    }
}

// ---------------------------------------------------------------- reduce 16 coltile partials -> idx, counts
__launch_bounds__(256)
__global__ void k_argmin_reduce(const float2* __restrict__ part, int* __restrict__ idxOut,
                                int* __restrict__ counts) {
    const int row = blockIdx.x * 256 + threadIdx.x;
    const float2* p = part + row * 16;
    float bv = p[0].x; int bi = __float_as_int(p[0].y);
#pragma unroll
    for (int t = 1; t < 16; ++t) {
        const float2 e = p[t];
        const int ii = __float_as_int(e.y);
        if (e.x < bv || (e.x == bv && ii < bi)) { bv = e.x; bi = ii; }
    }
    idxOut[row] = bi;
    atomicAdd(&counts[bi], 1);
}

// ---------------------------------------------------------------- quantized output + loss partial sums
__launch_bounds__(256)
__global__ void k_quant_loss(const float* __restrict__ inp, const float* __restrict__ emb,
                             const int* __restrict__ idx, float* __restrict__ outQ,
                             float* __restrict__ sumsq) {
    const int g  = blockIdx.x * 256 + threadIdx.x;
    const int e0 = g * 4;                       // element in [B][D][HW] layout
    const int b  = e0 >> 20;
    const int rem = e0 & 1048575;
    const int d  = rem >> 12;
    const int hw = rem & (HWSZ - 1);
    const int nb = (b << 12) + hw;

    const int4  i4 = *(const int4*)(idx + nb);
    const float4 xv = *(const float4*)(inp + e0);
    const float q0 = emb[i4.x * DDIM + d];
    const float q1 = emb[i4.y * DDIM + d];
    const float q2 = emb[i4.z * DDIM + d];
    const float q3 = emb[i4.w * DDIM + d];
    // outQ base (d_out+1) is not 16B aligned -> scalar stores
    outQ[e0 + 0] = q0; outQ[e0 + 1] = q1; outQ[e0 + 2] = q2; outQ[e0 + 3] = q3;

    const float d0 = q0 - xv.x, d1 = q1 - xv.y, d2 = q2 - xv.z, d3 = q3 - xv.w;
    float s = d0 * d0 + d1 * d1 + d2 * d2 + d3 * d3;
#pragma unroll
    for (int off = 32; off >= 1; off >>= 1) s += __shfl_down(s, off);
    __shared__ float wsum[4];
    const int lane = threadIdx.x & 63, w = threadIdx.x >> 6;
    if (lane == 0) wsum[w] = s;
    __syncthreads();
    if (threadIdx.x == 0) atomicAdd(sumsq, wsum[0] + wsum[1] + wsum[2] + wsum[3]);
}

// ---------------------------------------------------------------- scalars: loss + perplexity
__launch_bounds__(256)
__global__ void k_finalize(const int* __restrict__ counts, const float* __restrict__ sumsq,
                           float* __restrict__ out) {
    __shared__ float red[256];
    const int t = threadIdx.x;
    float s = 0.0f;
    for (int k = t; k < KCODES; k += 256) {
        const float p = (float)counts[k] * (1.0f / 65536.0f);
        s += p * logf(p + 1e-10f);
    }
    red[t] = s;
    __syncthreads();
    for (int off = 128; off >= 1; off >>= 1) {
        if (t < off) red[t] += red[t + off];
        __syncthreads();
    }
    if (t == 0) {
        out[OUT_PERP] = expf(-red[0]);
        out[OUT_LOSS] = 0.25f * sumsq[0] * (1.0f / 16777216.0f);
    }
}

// ---------------------------------------------------------------- one-hot encodings (float2: base is 8B- not 16B-aligned)
__launch_bounds__(256)
__global__ void k_onehot(const int* __restrict__ idx, float2* __restrict__ enc) {
    const int g = blockIdx.x * 256 + threadIdx.x;   // 67,108,864 threads
    const int n = g >> 10;                          // 1024 float2 per row of 2048
    const int c = (g & 1023) << 1;
    const int id = idx[n];
    float2 v;
    v.x = (c == id) ? 1.0f : 0.0f;
    v.y = (c + 1 == id) ? 1.0f : 0.0f;
    enc[g] = v;
}

// ---------------------------------------------------------------- launch
extern "C" void kernel_launch(void* const* d_in, const int* in_sizes, int n_in,
                              void* d_out, int out_size, void* d_ws, size_t ws_size,
                              hipStream_t stream) {
    const float* inp = (const float*)d_in[0];
    const float* emb = (const float*)d_in[1];
    float* out = (float*)d_out;

    int*    wsIdx  = (int*)d_ws;                 // 256 KB
    float2* part   = (float2*)(out + SCR_PART);
    float*  ET     = out + SCR_ET;
    float*  e2     = out + SCR_E2;
    int*    counts = (int*)(out + SCR_CNT);
    float*  sumsq  = out + SCR_SUM;

    // zero counts[2048] + sumsq[1] (contiguous)
    hipMemsetAsync((void*)counts, 0, (KCODES + 1) * sizeof(int), stream);

    k_transpose   <<<dim3(64, 8),   256, 0, stream>>>(emb, ET);
    k_e2          <<<512,           256, 0, stream>>>(emb, e2);
    k_argmin_part <<<dim3(16, 512), 256, 0, stream>>>(inp, ET, e2, part);
    k_argmin_reduce<<<256,          256, 0, stream>>>(part, wsIdx, counts);
    k_quant_loss  <<<16384,         256, 0, stream>>>(inp, emb, wsIdx, out + OUT_Q, sumsq);
    k_finalize    <<<1,             256, 0, stream>>>(counts, sumsq, out);
    k_onehot      <<<262144,        256, 0, stream>>>(wsIdx, (float2*)(out + OUT_ENC));
}

// Round 2
// 1283.346 us; speedup vs baseline: 1.3689x; 1.3689x over previous
//
#include <hip/hip_runtime.h>

// Problem: inputs [16,256,64,64] f32, embedding [2048,256] f32
#define NROWS   65536
#define KCODES  2048
#define DDIM    256
#define HWSZ    4096

// d_out float-element offsets (return order: loss, quantized, perplexity, encodings)
#define OUT_LOSS 0
#define OUT_Q    1
#define OUT_PERP 16777217
#define OUT_ENC  16777218

// Scratch carved from encodings region (k_onehot overwrites it last).
// SCR0 is 16B-aligned: (OUT_ENC+2)*4 % 16 == 0.
#define SCR0     (OUT_ENC + 2)
#define SCR_PART (SCR0)                 // float2 part[65536][16]      = 4,194,304 floats
#define SCR_XHI  (SCR0 + 4194304)       // _Float16 Xhi[65536*256]    = 8,388,608 floats
#define SCR_XLO  (SCR0 + 12582912)      // _Float16 Xlo[65536*256]
#define SCR_EHI  (SCR0 + 20971520)      // _Float16 Ehi[2048*256]     = 262,144 floats
#define SCR_ELO  (SCR0 + 21233664)
#define SCR_E2   (SCR0 + 21495808)      // float e2[2048]
#define SCR_CNT  (SCR0 + 21497856)      // int counts[2048]
#define SCR_SUM  (SCR0 + 21499904)      // float sumsq[1]

typedef _Float16 f16x8 __attribute__((ext_vector_type(8)));
typedef float    f32x4 __attribute__((ext_vector_type(4)));

__device__ __forceinline__ void gld16(const void* g, void* l) {
    // async global->LDS, 16B/lane; LDS dest = uniform base + lane*16
    __builtin_amdgcn_global_load_lds((const __attribute__((address_space(1))) void*)g,
                                     (__attribute__((address_space(3))) void*)l, 16, 0, 0);
}

// ------------------------------------------------ split X: [B,D,HW] f32 -> Xhi/Xlo [N,D] f16
__launch_bounds__(256)
__global__ void k_split(const float* __restrict__ inp, _Float16* __restrict__ Xhi,
                        _Float16* __restrict__ Xlo) {
    __shared__ float tile[32][33];
    const int hw0 = blockIdx.x * 32, d0 = blockIdx.y * 32, b = blockIdx.z;
    const int tx = threadIdx.x & 31, ty = threadIdx.x >> 5;
#pragma unroll
    for (int i = 0; i < 32; i += 8)
        tile[ty + i][tx] = inp[b * 1048576 + (d0 + ty + i) * 4096 + hw0 + tx];
    __syncthreads();
#pragma unroll
    for (int i = 0; i < 32; i += 8) {
        const float x = tile[tx][ty + i];
        const _Float16 h = (_Float16)x;
        const _Float16 lo = (_Float16)(x - (float)h);
        const int n = b * 4096 + hw0 + ty + i;
        Xhi[n * DDIM + d0 + tx] = h;
        Xlo[n * DDIM + d0 + tx] = lo;
    }
}

// ------------------------------------------------ split E + keep layout [K,D]
__launch_bounds__(256)
__global__ void k_esplit(const float* __restrict__ emb, _Float16* __restrict__ Ehi,
                         _Float16* __restrict__ Elo) {
    const int g = (blockIdx.x * 256 + threadIdx.x) * 4;   // 512 blocks
    const float4 v = *(const float4*)(emb + g);
    const float xs[4] = {v.x, v.y, v.z, v.w};
#pragma unroll
    for (int j = 0; j < 4; ++j) {
        const _Float16 h = (_Float16)xs[j];
        Ehi[g + j] = h;
        Elo[g + j] = (_Float16)(xs[j] - (float)h);
    }
}

// ------------------------------------------------ ||e||^2 (exact fp32)
__launch_bounds__(256)
__global__ void k_e2(const float* __restrict__ emb, float* __restrict__ e2) {
    const int wave = threadIdx.x >> 6;
    const int lane = threadIdx.x & 63;
    const int k = blockIdx.x * 4 + wave;
    const float4 v = *(const float4*)(emb + k * DDIM + lane * 4);
    float s = v.x * v.x + v.y * v.y + v.z * v.z + v.w * v.w;
#pragma unroll
    for (int off = 32; off >= 1; off >>= 1) s += __shfl_down(s, off);
    if (lane == 0) e2[k] = s;
}

// ------------------------------------------------ MFMA GEMM + fused partial argmin
// dot = hi*hi + hi*lo + lo*hi (fp16 split-3, ~1e-5 abs error); dist = e2 - 2*dot
__launch_bounds__(256, 2)
__global__ void k_argmin_mfma(const _Float16* __restrict__ Xhi, const _Float16* __restrict__ Xlo,
                              const _Float16* __restrict__ Ehi, const _Float16* __restrict__ Elo,
                              const float* __restrict__ e2, float2* __restrict__ part) {
    __shared__ _Float16 Ah[128 * 64], Al[128 * 64], Bh[128 * 64], Bl[128 * 64];
    __shared__ float redv[128][2];
    __shared__ int   redi[128][2];

    const int ct = blockIdx.x;            // 16 col tiles of 128 codes
    const int rb = blockIdx.y;            // 512 row blocks of 128 rows
    const int n0 = rb * 128, c0 = ct * 128;
    const int tid = threadIdx.x;
    const int w = tid >> 6, lane = tid & 63;
    const int wr = (w >> 1) * 64, wc = (w & 1) * 64;   // wave quadrant in 128x128
    const int lq = lane >> 4, lm = lane & 15;
    const int srow = w * 32;              // staging slab per wave
    const int lrow = lane >> 3;           // 0..7
    const int lcol = (lane & 7) * 8;      // f16 units

    f32x4 acc[4][4];
#pragma unroll
    for (int i = 0; i < 4; ++i)
#pragma unroll
        for (int j = 0; j < 4; ++j) acc[i][j] = (f32x4)(0.0f);

    for (int kt = 0; kt < 4; ++kt) {
        const int d0 = kt * 64;
        __syncthreads();
#pragma unroll
        for (int inst = 0; inst < 4; ++inst) {
            const int r = srow + inst * 8;
            const size_t ga = (size_t)(n0 + r + lrow) * DDIM + d0 + lcol;
            const size_t gb = (size_t)(c0 + r + lrow) * DDIM + d0 + lcol;
            gld16(Xhi + ga, &Ah[r * 64]);
            gld16(Xlo + ga, &Al[r * 64]);
            gld16(Ehi + gb, &Bh[r * 64]);
            gld16(Elo + gb, &Bl[r * 64]);
        }
        __syncthreads();
#pragma unroll
        for (int ks = 0; ks < 64; ks += 32) {
            const int ko = ks + lq * 8;
            f16x8 ah[4], al[4], bh[4], bl[4];
#pragma unroll
            for (int t = 0; t < 4; ++t) {
                ah[t] = *(const f16x8*)&Ah[(wr + t * 16 + lm) * 64 + ko];
                al[t] = *(const f16x8*)&Al[(wr + t * 16 + lm) * 64 + ko];
                bh[t] = *(const f16x8*)&Bh[(wc + t * 16 + lm) * 64 + ko];
                bl[t] = *(const f16x8*)&Bl[(wc + t * 16 + lm) * 64 + ko];
            }
#pragma unroll
            for (int i = 0; i < 4; ++i)
#pragma unroll
                for (int j = 0; j < 4; ++j) {
                    acc[i][j] = __builtin_amdgcn_mfma_f32_16x16x32_f16(ah[i], bh[j], acc[i][j], 0, 0, 0);
                    acc[i][j] = __builtin_amdgcn_mfma_f32_16x16x32_f16(ah[i], bl[j], acc[i][j], 0, 0, 0);
                    acc[i][j] = __builtin_amdgcn_mfma_f32_16x16x32_f16(al[i], bh[j], acc[i][j], 0, 0, 0);
                }
        }
    }

    // epilogue: dist = e2[c] - 2*dot; per-row argmin.
    // C layout (16x16x32): col = lm, row = lq*4 + reg
    float e2v[4];
#pragma unroll
    for (int j = 0; j < 4; ++j) e2v[j] = e2[c0 + wc + j * 16 + lm];

#pragma unroll
    for (int i = 0; i < 4; ++i) {
#pragma unroll
        for (int r = 0; r < 4; ++r) {
            float bv = 3.402823466e38f; int bi = 0;
#pragma unroll
            for (int j = 0; j < 4; ++j) {
                const float dist = fmaf(-2.0f, acc[i][j][r], e2v[j]);
                const int ci = c0 + wc + j * 16 + lm;
                if (dist < bv || (dist == bv && ci < bi)) { bv = dist; bi = ci; }
            }
#pragma unroll
            for (int off = 1; off < 16; off <<= 1) {
                const float ov = __shfl_xor(bv, off);
                const int   oi = __shfl_xor(bi, off);
                if (ov < bv || (ov == bv && oi < bi)) { bv = ov; bi = oi; }
            }
            if (lm == 0) {
                const int row = wr + i * 16 + lq * 4 + r;
                redv[row][w & 1] = bv;
                redi[row][w & 1] = bi;
            }
        }
    }
    __syncthreads();
    if (tid < 128) {
        float bv = redv[tid][0]; int bi = redi[tid][0];
        const float v1 = redv[tid][1]; const int i1 = redi[tid][1];
        if (v1 < bv || (v1 == bv && i1 < bi)) { bv = v1; bi = i1; }
        part[(size_t)(n0 + tid) * 16 + ct] = make_float2(bv, __int_as_float(bi));
    }
}

// ------------------------------------------------ reduce 16 coltile partials -> idx, counts
__launch_bounds__(256)
__global__ void k_argmin_reduce(const float2* __restrict__ part, int* __restrict__ idxOut,
                                int* __restrict__ counts) {
    const int row = blockIdx.x * 256 + threadIdx.x;
    const float2* p = part + (size_t)row * 16;
    float bv = p[0].x; int bi = __float_as_int(p[0].y);
#pragma unroll
    for (int t = 1; t < 16; ++t) {
        const float2 e = p[t];
        const int ii = __float_as_int(e.y);
        if (e.x < bv || (e.x == bv && ii < bi)) { bv = e.x; bi = ii; }
    }
    idxOut[row] = bi;
    atomicAdd(&counts[bi], 1);
}

// ------------------------------------------------ quantized output + loss partial sums
__launch_bounds__(256)
__global__ void k_quant_loss(const float* __restrict__ inp, const float* __restrict__ emb,
                             const int* __restrict__ idx, float* __restrict__ outQ,
                             float* __restrict__ sumsq) {
    const int g  = blockIdx.x * 256 + threadIdx.x;
    const int e0 = g * 4;
    const int b  = e0 >> 20;
    const int rem = e0 & 1048575;
    const int d  = rem >> 12;
    const int hw = rem & (HWSZ - 1);
    const int nb = (b << 12) + hw;

    const int4  i4 = *(const int4*)(idx + nb);
    const float4 xv = *(const float4*)(inp + e0);
    const float q0 = emb[i4.x * DDIM + d];
    const float q1 = emb[i4.y * DDIM + d];
    const float q2 = emb[i4.z * DDIM + d];
    const float q3 = emb[i4.w * DDIM + d];
    outQ[e0 + 0] = q0; outQ[e0 + 1] = q1; outQ[e0 + 2] = q2; outQ[e0 + 3] = q3;

    const float d0 = q0 - xv.x, d1 = q1 - xv.y, d2 = q2 - xv.z, d3 = q3 - xv.w;
    float s = d0 * d0 + d1 * d1 + d2 * d2 + d3 * d3;
#pragma unroll
    for (int off = 32; off >= 1; off >>= 1) s += __shfl_down(s, off);
    __shared__ float wsum[4];
    const int lane = threadIdx.x & 63, wv = threadIdx.x >> 6;
    if (lane == 0) wsum[wv] = s;
    __syncthreads();
    if (threadIdx.x == 0) atomicAdd(sumsq, wsum[0] + wsum[1] + wsum[2] + wsum[3]);
}

// ------------------------------------------------ scalars
__launch_bounds__(256)
__global__ void k_finalize(const int* __restrict__ counts, const float* __restrict__ sumsq,
                           float* __restrict__ out) {
    __shared__ float red[256];
    const int t = threadIdx.x;
    float s = 0.0f;
    for (int k = t; k < KCODES; k += 256) {
        const float p = (float)counts[k] * (1.0f / 65536.0f);
        s += p * logf(p + 1e-10f);
    }
    red[t] = s;
    __syncthreads();
    for (int off = 128; off >= 1; off >>= 1) {
        if (t < off) red[t] += red[t + off];
        __syncthreads();
    }
    if (t == 0) {
        out[OUT_PERP] = expf(-red[0]);
        out[OUT_LOSS] = 0.25f * sumsq[0] * (1.0f / 16777216.0f);
    }
}

// ------------------------------------------------ one-hot encodings (float2: base 8B-aligned only)
__launch_bounds__(256)
__global__ void k_onehot(const int* __restrict__ idx, float2* __restrict__ enc) {
    const int g = blockIdx.x * 256 + threadIdx.x;
    const int n = g >> 10;
    const int c = (g & 1023) << 1;
    const int id = idx[n];
    float2 v;
    v.x = (c == id) ? 1.0f : 0.0f;
    v.y = (c + 1 == id) ? 1.0f : 0.0f;
    enc[g] = v;
}

// ------------------------------------------------ launch
extern "C" void kernel_launch(void* const* d_in, const int* in_sizes, int n_in,
                              void* d_out, int out_size, void* d_ws, size_t ws_size,
                              hipStream_t stream) {
    const float* inp = (const float*)d_in[0];
    const float* emb = (const float*)d_in[1];
    float* out = (float*)d_out;

    int*       wsIdx  = (int*)d_ws;
    float2*    part   = (float2*)(out + SCR_PART);
    _Float16*  Xhi    = (_Float16*)(out + SCR_XHI);
    _Float16*  Xlo    = (_Float16*)(out + SCR_XLO);
    _Float16*  Ehi    = (_Float16*)(out + SCR_EHI);
    _Float16*  Elo    = (_Float16*)(out + SCR_ELO);
    float*     e2     = out + SCR_E2;
    int*       counts = (int*)(out + SCR_CNT);
    float*     sumsq  = out + SCR_SUM;

    hipMemsetAsync((void*)counts, 0, (KCODES + 1) * sizeof(int), stream);

    k_split        <<<dim3(128, 8, 16), 256, 0, stream>>>(inp, Xhi, Xlo);
    k_esplit       <<<512,              256, 0, stream>>>(emb, Ehi, Elo);
    k_e2           <<<512,              256, 0, stream>>>(emb, e2);
    k_argmin_mfma  <<<dim3(16, 512),    256, 0, stream>>>(Xhi, Xlo, Ehi, Elo, e2, part);
    k_argmin_reduce<<<256,              256, 0, stream>>>(part, wsIdx, counts);
    k_quant_loss   <<<16384,            256, 0, stream>>>(inp, emb, wsIdx, out + OUT_Q, sumsq);
    k_finalize     <<<1,                256, 0, stream>>>(counts, sumsq, out);
    k_onehot       <<<262144,           256, 0, stream>>>(wsIdx, (float2*)(out + OUT_ENC));
}

// Round 3
// 1155.439 us; speedup vs baseline: 1.5204x; 1.1107x over previous
//
#include <hip/hip_runtime.h>

// Problem: inputs [16,256,64,64] f32, embedding [2048,256] f32
#define NROWS   65536
#define KCODES  2048
#define DDIM    256
#define HWSZ    4096

// d_out float-element offsets (return order: loss, quantized, perplexity, encodings)
#define OUT_LOSS 0
#define OUT_Q    1
#define OUT_PERP 16777217
#define OUT_ENC  16777218

// Scratch carved from encodings region (k_onehot overwrites it last).
// SCR0 is 16B-aligned: (OUT_ENC+2)*4 % 16 == 0.
#define SCR0     (OUT_ENC + 2)
#define SCR_PART (SCR0)                 // float2 part[65536][16]      = 4,194,304 floats
#define SCR_XHI  (SCR0 + 4194304)       // _Float16 Xhi[65536*256]    = 8,388,608 floats
#define SCR_XLO  (SCR0 + 12582912)      // _Float16 Xlo[65536*256]
#define SCR_EHI  (SCR0 + 20971520)      // _Float16 Ehi[2048*256]     = 262,144 floats
#define SCR_ELO  (SCR0 + 21233664)
#define SCR_E2   (SCR0 + 21495808)      // float e2[2048]
#define SCR_CNT  (SCR0 + 21497856)      // int counts[2048]
#define SCR_SUM  (SCR0 + 21499904)      // float sumsq[1]

typedef _Float16 f16x8 __attribute__((ext_vector_type(8)));
typedef float    f32x4 __attribute__((ext_vector_type(4)));

__device__ __forceinline__ void gld16(const void* g, void* l) {
    // async global->LDS, 16B/lane; LDS dest = wave-uniform base + lane*16
    __builtin_amdgcn_global_load_lds((const __attribute__((address_space(1))) void*)g,
                                     (__attribute__((address_space(3))) void*)l, 16, 0, 0);
}

// ------------------------------------------------ split X: [B,D,HW] f32 -> Xhi/Xlo [N,D] f16
__launch_bounds__(256)
__global__ void k_split(const float* __restrict__ inp, _Float16* __restrict__ Xhi,
                        _Float16* __restrict__ Xlo) {
    __shared__ float tile[32][33];
    const int hw0 = blockIdx.x * 32, d0 = blockIdx.y * 32, b = blockIdx.z;
    const int tx = threadIdx.x & 31, ty = threadIdx.x >> 5;
#pragma unroll
    for (int i = 0; i < 32; i += 8)
        tile[ty + i][tx] = inp[b * 1048576 + (d0 + ty + i) * 4096 + hw0 + tx];
    __syncthreads();
#pragma unroll
    for (int i = 0; i < 32; i += 8) {
        const float x = tile[tx][ty + i];
        const _Float16 h = (_Float16)x;
        const _Float16 lo = (_Float16)(x - (float)h);
        const int n = b * 4096 + hw0 + ty + i;
        Xhi[n * DDIM + d0 + tx] = h;
        Xlo[n * DDIM + d0 + tx] = lo;
    }
}

// ------------------------------------------------ split E [K,D]
__launch_bounds__(256)
__global__ void k_esplit(const float* __restrict__ emb, _Float16* __restrict__ Ehi,
                         _Float16* __restrict__ Elo) {
    const int g = (blockIdx.x * 256 + threadIdx.x) * 4;   // 512 blocks
    const float4 v = *(const float4*)(emb + g);
    const float xs[4] = {v.x, v.y, v.z, v.w};
#pragma unroll
    for (int j = 0; j < 4; ++j) {
        const _Float16 h = (_Float16)xs[j];
        Ehi[g + j] = h;
        Elo[g + j] = (_Float16)(xs[j] - (float)h);
    }
}

// ------------------------------------------------ ||e||^2 (exact fp32)
__launch_bounds__(256)
__global__ void k_e2(const float* __restrict__ emb, float* __restrict__ e2) {
    const int wave = threadIdx.x >> 6;
    const int lane = threadIdx.x & 63;
    const int k = blockIdx.x * 4 + wave;
    const float4 v = *(const float4*)(emb + k * DDIM + lane * 4);
    float s = v.x * v.x + v.y * v.y + v.z * v.z + v.w * v.w;
#pragma unroll
    for (int off = 32; off >= 1; off >>= 1) s += __shfl_down(s, off);
    if (lane == 0) e2[k] = s;
}

// ------------------------------------------------ MFMA GEMM + fused partial argmin
// Virtual K = 768: seg 0: Xhi*Ehi, seg 1: Xhi*Elo, seg 2: Xlo*Ehi  (split-3 fp16)
// dist = e2 - 2*dot. LDS = 2 x 128x64 f16 = 32 KB, XOR-swizzled chunks (bank-conflict-free).
__launch_bounds__(256, 4)
__global__ void k_argmin_mfma(const _Float16* __restrict__ Xhi, const _Float16* __restrict__ Xlo,
                              const _Float16* __restrict__ Ehi, const _Float16* __restrict__ Elo,
                              const float* __restrict__ e2, float2* __restrict__ part) {
    __shared__ _Float16 Ah[128 * 64];   // 16 KB (argmin scratch aliased here post-loop)
    __shared__ _Float16 Bh[128 * 64];   // 16 KB

    const int ct = blockIdx.x;            // 16 col tiles of 128 codes
    const int rb = blockIdx.y;            // 512 row blocks of 128 rows
    const int n0 = rb * 128, c0 = ct * 128;
    const int tid = threadIdx.x;
    const int w = tid >> 6, lane = tid & 63;
    const int wr = (w >> 1) * 64, wc = (w & 1) * 64;   // wave quadrant of 128x128
    const int lq = lane >> 4, lm = lane & 15;
    const int r = lane >> 3;              // staging: row-in-8 (0..7)
    const int c = lane & 7;               // staging: 16B chunk (0..7)
    const int gch = c ^ r;                // XOR-swizzled source chunk

    f32x4 acc[4][4];
#pragma unroll
    for (int i = 0; i < 4; ++i)
#pragma unroll
        for (int j = 0; j < 4; ++j) acc[i][j] = (f32x4)(0.0f);

    for (int kt = 0; kt < 12; ++kt) {
        const int seg = kt >> 2;
        const int d0  = (kt & 3) * 64;
        const _Float16* __restrict__ As = (seg < 2) ? Xhi : Xlo;
        const _Float16* __restrict__ Bs = (seg == 1) ? Elo : Ehi;

        __syncthreads();
#pragma unroll
        for (int i = 0; i < 4; ++i) {
            const int Row = i * 32 + w * 8 + r;
            gld16(As + (size_t)(n0 + Row) * DDIM + d0 + gch * 8, &Ah[(i * 32 + w * 8) * 64]);
            gld16(Bs + (size_t)(c0 + Row) * DDIM + d0 + gch * 8, &Bh[(i * 32 + w * 8) * 64]);
        }
        __syncthreads();

#pragma unroll
        for (int s = 0; s < 2; ++s) {
            const int wch = s * 4 + lq;   // wanted 16B chunk before swizzle
            f16x8 af[4], bf[4];
#pragma unroll
            for (int t = 0; t < 4; ++t) {
                const int Ra = wr + t * 16 + lm;
                const int Rb = wc + t * 16 + lm;
                af[t] = *(const f16x8*)&Ah[Ra * 64 + ((wch ^ (Ra & 7)) * 8)];
                bf[t] = *(const f16x8*)&Bh[Rb * 64 + ((wch ^ (Rb & 7)) * 8)];
            }
#pragma unroll
            for (int i = 0; i < 4; ++i)
#pragma unroll
                for (int j = 0; j < 4; ++j)
                    acc[i][j] = __builtin_amdgcn_mfma_f32_16x16x32_f16(af[i], bf[j], acc[i][j], 0, 0, 0);
        }
    }

    // epilogue: dist = e2[c] - 2*dot; per-row argmin.
    // C layout (16x16x32): col = lm, row = lq*4 + reg
    float e2v[4];
#pragma unroll
    for (int j = 0; j < 4; ++j) e2v[j] = e2[c0 + wc + j * 16 + lm];

    float bestv[4][4]; int besti[4][4];
#pragma unroll
    for (int i = 0; i < 4; ++i)
#pragma unroll
        for (int rr = 0; rr < 4; ++rr) {
            float bv = 3.402823466e38f; int bi = 0;
#pragma unroll
            for (int j = 0; j < 4; ++j) {
                const float dist = fmaf(-2.0f, acc[i][j][rr], e2v[j]);
                const int ci = c0 + wc + j * 16 + lm;
                if (dist < bv || (dist == bv && ci < bi)) { bv = dist; bi = ci; }
            }
#pragma unroll
            for (int off = 1; off < 16; off <<= 1) {
                const float ov = __shfl_xor(bv, off);
                const int   oi = __shfl_xor(bi, off);
                if (ov < bv || (ov == bv && oi < bi)) { bv = ov; bi = oi; }
            }
            bestv[i][rr] = bv; besti[i][rr] = bi;
        }

    __syncthreads();                       // all LDS frag reads done -> safe to alias
    float* redv = (float*)Ah;              // [128][2]
    int*   redi = (int*)(Ah + 512);        // [128][2]
    if (lm == 0) {
#pragma unroll
        for (int i = 0; i < 4; ++i)
#pragma unroll
            for (int rr = 0; rr < 4; ++rr) {
                const int row = wr + i * 16 + lq * 4 + rr;
                redv[row * 2 + (w & 1)] = bestv[i][rr];
                redi[row * 2 + (w & 1)] = besti[i][rr];
            }
    }
    __syncthreads();
    if (tid < 128) {
        float bv = redv[tid * 2]; int bi = redi[tid * 2];
        const float v1 = redv[tid * 2 + 1]; const int i1 = redi[tid * 2 + 1];
        if (v1 < bv || (v1 == bv && i1 < bi)) { bv = v1; bi = i1; }
        part[(size_t)(n0 + tid) * 16 + ct] = make_float2(bv, __int_as_float(bi));
    }
}

// ------------------------------------------------ reduce 16 coltile partials -> idx, counts
__launch_bounds__(256)
__global__ void k_argmin_reduce(const float2* __restrict__ part, int* __restrict__ idxOut,
                                int* __restrict__ counts) {
    const int row = blockIdx.x * 256 + threadIdx.x;
    const float2* p = part + (size_t)row * 16;
    float bv = p[0].x; int bi = __float_as_int(p[0].y);
#pragma unroll
    for (int t = 1; t < 16; ++t) {
        const float2 e = p[t];
        const int ii = __float_as_int(e.y);
        if (e.x < bv || (e.x == bv && ii < bi)) { bv = e.x; bi = ii; }
    }
    idxOut[row] = bi;
    atomicAdd(&counts[bi], 1);
}

// ------------------------------------------------ quantized output + loss partial sums
__launch_bounds__(256)
__global__ void k_quant_loss(const float* __restrict__ inp, const float* __restrict__ emb,
                             const int* __restrict__ idx, float* __restrict__ outQ,
                             float* __restrict__ sumsq) {
    const int g  = blockIdx.x * 256 + threadIdx.x;
    const int e0 = g * 4;
    const int b  = e0 >> 20;
    const int rem = e0 & 1048575;
    const int d  = rem >> 12;
    const int hw = rem & (HWSZ - 1);
    const int nb = (b << 12) + hw;

    const int4  i4 = *(const int4*)(idx + nb);
    const float4 xv = *(const float4*)(inp + e0);
    const float q0 = emb[i4.x * DDIM + d];
    const float q1 = emb[i4.y * DDIM + d];
    const float q2 = emb[i4.z * DDIM + d];
    const float q3 = emb[i4.w * DDIM + d];
    outQ[e0 + 0] = q0; outQ[e0 + 1] = q1; outQ[e0 + 2] = q2; outQ[e0 + 3] = q3;

    const float d0 = q0 - xv.x, d1 = q1 - xv.y, d2 = q2 - xv.z, d3 = q3 - xv.w;
    float s = d0 * d0 + d1 * d1 + d2 * d2 + d3 * d3;
#pragma unroll
    for (int off = 32; off >= 1; off >>= 1) s += __shfl_down(s, off);
    __shared__ float wsum[4];
    const int lane = threadIdx.x & 63, wv = threadIdx.x >> 6;
    if (lane == 0) wsum[wv] = s;
    __syncthreads();
    if (threadIdx.x == 0) atomicAdd(sumsq, wsum[0] + wsum[1] + wsum[2] + wsum[3]);
}

// ------------------------------------------------ scalars
__launch_bounds__(256)
__global__ void k_finalize(const int* __restrict__ counts, const float* __restrict__ sumsq,
                           float* __restrict__ out) {
    __shared__ float red[256];
    const int t = threadIdx.x;
    float s = 0.0f;
    for (int k = t; k < KCODES; k += 256) {
        const float p = (float)counts[k] * (1.0f / 65536.0f);
        s += p * logf(p + 1e-10f);
    }
    red[t] = s;
    __syncthreads();
    for (int off = 128; off >= 1; off >>= 1) {
        if (t < off) red[t] += red[t + off];
        __syncthreads();
    }
    if (t == 0) {
        out[OUT_PERP] = expf(-red[0]);
        out[OUT_LOSS] = 0.25f * sumsq[0] * (1.0f / 16777216.0f);
    }
}

// ------------------------------------------------ one-hot encodings: 1 block per row,
// idx broadcast via scalar load; 4 coalesced float2 stores per thread
__launch_bounds__(256)
__global__ void k_onehot(const int* __restrict__ idx, float2* __restrict__ enc) {
    const int n = blockIdx.x;
    const int id = idx[n];
    float2* rowp = enc + (size_t)n * 1024;
#pragma unroll
    for (int k = 0; k < 4; ++k) {
        const int col2 = k * 256 + threadIdx.x;
        const int cc = col2 * 2;
        float2 v;
        v.x = (cc == id) ? 1.0f : 0.0f;
        v.y = (cc + 1 == id) ? 1.0f : 0.0f;
        rowp[col2] = v;
    }
}

// ------------------------------------------------ launch
extern "C" void kernel_launch(void* const* d_in, const int* in_sizes, int n_in,
                              void* d_out, int out_size, void* d_ws, size_t ws_size,
                              hipStream_t stream) {
    const float* inp = (const float*)d_in[0];
    const float* emb = (const float*)d_in[1];
    float* out = (float*)d_out;

    int*       wsIdx  = (int*)d_ws;
    float2*    part   = (float2*)(out + SCR_PART);
    _Float16*  Xhi    = (_Float16*)(out + SCR_XHI);
    _Float16*  Xlo    = (_Float16*)(out + SCR_XLO);
    _Float16*  Ehi    = (_Float16*)(out + SCR_EHI);
    _Float16*  Elo    = (_Float16*)(out + SCR_ELO);
    float*     e2     = out + SCR_E2;
    int*       counts = (int*)(out + SCR_CNT);
    float*     sumsq  = out + SCR_SUM;

    hipMemsetAsync((void*)counts, 0, (KCODES + 1) * sizeof(int), stream);

    k_split        <<<dim3(128, 8, 16), 256, 0, stream>>>(inp, Xhi, Xlo);
    k_esplit       <<<512,              256, 0, stream>>>(emb, Ehi, Elo);
    k_e2           <<<512,              256, 0, stream>>>(emb, e2);
    k_argmin_mfma  <<<dim3(16, 512),    256, 0, stream>>>(Xhi, Xlo, Ehi, Elo, e2, part);
    k_argmin_reduce<<<256,              256, 0, stream>>>(part, wsIdx, counts);
    k_quant_loss   <<<16384,            256, 0, stream>>>(inp, emb, wsIdx, out + OUT_Q, sumsq);
    k_finalize     <<<1,                256, 0, stream>>>(counts, sumsq, out);
    k_onehot       <<<65536,            256, 0, stream>>>(wsIdx, (float2*)(out + OUT_ENC));
}

// Round 4
// 1131.947 us; speedup vs baseline: 1.5520x; 1.0208x over previous
//
#include <hip/hip_runtime.h>

// Problem: inputs [16,256,64,64] f32, embedding [2048,256] f32
#define NROWS   65536
#define KCODES  2048
#define DDIM    256
#define HWSZ    4096

// d_out float-element offsets (return order: loss, quantized, perplexity, encodings)
#define OUT_LOSS 0
#define OUT_Q    1
#define OUT_PERP 16777217
#define OUT_ENC  16777218

// Scratch carved from encodings region (k_onehot overwrites it last).
// SCR0 is 16B-aligned: (OUT_ENC+2)*4 % 16 == 0.
#define SCR0     (OUT_ENC + 2)
#define SCR_PART (SCR0)                 // float4 part[65536][16]     = 4,194,304 floats (16 MB)
#define SCR_XHI  (SCR0 + 4194304)       // _Float16 Xhi[65536*256]   = 8,388,608 floats
#define SCR_XLO  (SCR0 + 12582912)      // _Float16 Xlo[65536*256]
#define SCR_EHI  (SCR0 + 20971520)      // _Float16 Ehi[2048*256]    = 262,144 floats
#define SCR_E2   (SCR0 + 21233664)      // float e2[2048]
#define SCR_CNT  (SCR0 + 21235712)      // int counts[2048]
#define SCR_SUM  (SCR0 + 21237760)      // float sumsq[1]
#define SCR_CAND (SCR0 + 21237764)      // int4 cand[65536] (1 MB), 16B-aligned

typedef _Float16 f16x8 __attribute__((ext_vector_type(8)));
typedef _Float16 f16x4 __attribute__((ext_vector_type(4)));
typedef float    f32x4 __attribute__((ext_vector_type(4)));

__device__ __forceinline__ void gld16(const void* g, void* l) {
    __builtin_amdgcn_global_load_lds((const __attribute__((address_space(1))) void*)g,
                                     (__attribute__((address_space(3))) void*)l, 16, 0, 0);
}

// ------------------------------------------------ split X: [B,D,HW] f32 -> Xhi/Xlo [N,D] f16
__launch_bounds__(256)
__global__ void k_split(const float* __restrict__ inp, _Float16* __restrict__ Xhi,
                        _Float16* __restrict__ Xlo) {
    __shared__ float tile[32][33];
    const int hw0 = blockIdx.x * 32, d0 = blockIdx.y * 32, b = blockIdx.z;
    const int tx = threadIdx.x & 31, ty = threadIdx.x >> 5;
#pragma unroll
    for (int i = 0; i < 32; i += 8)
        tile[ty + i][tx] = inp[b * 1048576 + (d0 + ty + i) * 4096 + hw0 + tx];
    __syncthreads();
#pragma unroll
    for (int i = 0; i < 32; i += 8) {
        const float x = tile[tx][ty + i];
        const _Float16 h = (_Float16)x;
        const _Float16 lo = (_Float16)(x - (float)h);
        const int n = b * 4096 + hw0 + ty + i;
        Xhi[n * DDIM + d0 + tx] = h;
        Xlo[n * DDIM + d0 + tx] = lo;
    }
}

// ------------------------------------------------ Ehi (hi plane only; refine uses fp32 emb)
__launch_bounds__(256)
__global__ void k_esplit(const float* __restrict__ emb, _Float16* __restrict__ Ehi) {
    const int g = (blockIdx.x * 256 + threadIdx.x) * 4;   // 512 blocks
    const float4 v = *(const float4*)(emb + g);
    Ehi[g + 0] = (_Float16)v.x; Ehi[g + 1] = (_Float16)v.y;
    Ehi[g + 2] = (_Float16)v.z; Ehi[g + 3] = (_Float16)v.w;
}

// ------------------------------------------------ ||e||^2 (exact fp32)
__launch_bounds__(256)
__global__ void k_e2(const float* __restrict__ emb, float* __restrict__ e2) {
    const int wave = threadIdx.x >> 6;
    const int lane = threadIdx.x & 63;
    const int k = blockIdx.x * 4 + wave;
    const float4 v = *(const float4*)(emb + k * DDIM + lane * 4);
    float s = v.x * v.x + v.y * v.y + v.z * v.z + v.w * v.w;
#pragma unroll
    for (int off = 32; off >= 1; off >>= 1) s += __shfl_down(s, off);
    if (lane == 0) e2[k] = s;
}

// top-2 pair merge: (m1,i1,m2,i2) <- merge with (n1,j1,n2,j2); tie -> smaller idx
#define MERGE2(m1,i1,m2,i2,n1,j1,n2,j2)                                   \
    {                                                                     \
        const bool w_ = ((n1) < (m1)) || ((n1) == (m1) && (j1) < (i1));   \
        const float w1_ = w_ ? (n1) : (m1); const int wi_ = w_ ? (j1) : (i1); \
        const float l1_ = w_ ? (m1) : (n1); const int li_ = w_ ? (i1) : (j1); \
        const float c2_ = w_ ? (n2) : (m2); const int ci_ = w_ ? (j2) : (i2); \
        const bool s_ = ((c2_) < (l1_)) || ((c2_) == (l1_) && (ci_) < (li_)); \
        (m1) = w1_; (i1) = wi_;                                           \
        (m2) = s_ ? c2_ : l1_; (i2) = s_ ? ci_ : li_;                     \
    }

// ------------------------------------------------ stage-1: hi*hi GEMM (K=256) + top-2 per (row, coltile)
// dist_approx = e2 - 2*(xhi . ehi); LDS 32 KB, XOR-swizzled chunks
__launch_bounds__(256, 4)
__global__ void k_argmin_mfma(const _Float16* __restrict__ Xhi, const _Float16* __restrict__ Ehi,
                              const float* __restrict__ e2, float4* __restrict__ part) {
    __shared__ _Float16 Ah[128 * 64];   // 16 KB (reduction scratch aliased post-loop)
    __shared__ _Float16 Bh[128 * 64];   // 16 KB

    const int ct = blockIdx.x;            // 16 col tiles of 128 codes
    const int rb = blockIdx.y;            // 512 row blocks of 128 rows
    const int n0 = rb * 128, c0 = ct * 128;
    const int tid = threadIdx.x;
    const int w = tid >> 6, lane = tid & 63;
    const int wr = (w >> 1) * 64, wc = (w & 1) * 64;
    const int lq = lane >> 4, lm = lane & 15;
    const int r = lane >> 3;
    const int c = lane & 7;
    const int gch = c ^ r;

    f32x4 acc[4][4];
#pragma unroll
    for (int i = 0; i < 4; ++i)
#pragma unroll
        for (int j = 0; j < 4; ++j) acc[i][j] = (f32x4)(0.0f);

    for (int kt = 0; kt < 4; ++kt) {
        const int d0 = kt * 64;
        __syncthreads();
#pragma unroll
        for (int i = 0; i < 4; ++i) {
            const int Row = i * 32 + w * 8 + r;
            gld16(Xhi + (size_t)(n0 + Row) * DDIM + d0 + gch * 8, &Ah[(i * 32 + w * 8) * 64]);
            gld16(Ehi + (size_t)(c0 + Row) * DDIM + d0 + gch * 8, &Bh[(i * 32 + w * 8) * 64]);
        }
        __syncthreads();
#pragma unroll
        for (int s = 0; s < 2; ++s) {
            const int wch = s * 4 + lq;
            f16x8 af[4], bf[4];
#pragma unroll
            for (int t = 0; t < 4; ++t) {
                const int Ra = wr + t * 16 + lm;
                const int Rb = wc + t * 16 + lm;
                af[t] = *(const f16x8*)&Ah[Ra * 64 + ((wch ^ (Ra & 7)) * 8)];
                bf[t] = *(const f16x8*)&Bh[Rb * 64 + ((wch ^ (Rb & 7)) * 8)];
            }
#pragma unroll
            for (int i = 0; i < 4; ++i)
#pragma unroll
                for (int j = 0; j < 4; ++j)
                    acc[i][j] = __builtin_amdgcn_mfma_f32_16x16x32_f16(af[i], bf[j], acc[i][j], 0, 0, 0);
        }
    }

    // epilogue: per-row TOP-2 over this wave's 64 cols.
    // C layout (16x16x32): col = lm, row = lq*4 + reg
    float e2v[4];
#pragma unroll
    for (int j = 0; j < 4; ++j) e2v[j] = e2[c0 + wc + j * 16 + lm];

    float m1a[4][4], m2a[4][4]; int i1a[4][4], i2a[4][4];
#pragma unroll
    for (int i = 0; i < 4; ++i)
#pragma unroll
        for (int rr = 0; rr < 4; ++rr) {
            const float d0v = fmaf(-2.0f, acc[i][0][rr], e2v[0]);
            const float d1v = fmaf(-2.0f, acc[i][1][rr], e2v[1]);
            const float d2v = fmaf(-2.0f, acc[i][2][rr], e2v[2]);
            const float d3v = fmaf(-2.0f, acc[i][3][rr], e2v[3]);
            const int id0 = c0 + wc + 0 * 16 + lm, id1 = c0 + wc + 1 * 16 + lm;
            const int id2 = c0 + wc + 2 * 16 + lm, id3 = c0 + wc + 3 * 16 + lm;
            // per-lane top-2 of 4 (idx ascending with j, so value ties keep lower j)
            const bool p = d1v < d0v;
            const float a1 = p ? d1v : d0v; const int a1i = p ? id1 : id0;
            const float a2 = p ? d0v : d1v; const int a2i = p ? id0 : id1;
            const bool q = d3v < d2v;
            const float b1 = q ? d3v : d2v; const int b1i = q ? id3 : id2;
            const float b2 = q ? d2v : d3v; const int b2i = q ? id2 : id3;
            float m1 = a1; int i1 = a1i; float m2 = a2; int i2 = a2i;
            MERGE2(m1, i1, m2, i2, b1, b1i, b2, b2i);
            // xor-shuffle merge across 16 lm lanes
#pragma unroll
            for (int off = 1; off < 16; off <<= 1) {
                const float n1 = __shfl_xor(m1, off); const int j1 = __shfl_xor(i1, off);
                const float n2 = __shfl_xor(m2, off); const int j2 = __shfl_xor(i2, off);
                MERGE2(m1, i1, m2, i2, n1, j1, n2, j2);
            }
            m1a[i][rr] = m1; i1a[i][rr] = i1; m2a[i][rr] = m2; i2a[i][rr] = i2;
        }

    __syncthreads();                       // all LDS frag reads done -> safe to alias
    float4* red = (float4*)Ah;             // [128][2]
    if (lm == 0) {
#pragma unroll
        for (int i = 0; i < 4; ++i)
#pragma unroll
            for (int rr = 0; rr < 4; ++rr) {
                const int row = wr + i * 16 + lq * 4 + rr;
                red[row * 2 + (w & 1)] = make_float4(m1a[i][rr], __int_as_float(i1a[i][rr]),
                                                     m2a[i][rr], __int_as_float(i2a[i][rr]));
            }
    }
    __syncthreads();
    if (tid < 128) {
        const float4 A = red[tid * 2];
        const float4 B = red[tid * 2 + 1];
        float m1 = A.x; int i1 = __float_as_int(A.y);
        float m2 = A.z; int i2 = __float_as_int(A.w);
        MERGE2(m1, i1, m2, i2, B.x, __float_as_int(B.y), B.z, __float_as_int(B.w));
        part[(size_t)(n0 + tid) * 16 + ct] = make_float4(m1, __int_as_float(i1),
                                                         m2, __int_as_float(i2));
    }
}

// ------------------------------------------------ merge 16 coltile top-2s -> global top-4 candidates
__launch_bounds__(256)
__global__ void k_reduce(const float4* __restrict__ part, int4* __restrict__ cand) {
    const int row = blockIdx.x * 256 + threadIdx.x;
    const float4* p = part + (size_t)row * 16;
    float tv[4] = {3.4e38f, 3.4e38f, 3.4e38f, 3.4e38f};
    int   ti[4] = {0x7fffffff, 0x7fffffff, 0x7fffffff, 0x7fffffff};
#pragma unroll 4
    for (int t = 0; t < 16; ++t) {
        const float4 e = p[t];
#pragma unroll
        for (int h = 0; h < 2; ++h) {
            float cv = h ? e.z : e.x;
            int   ci = __float_as_int(h ? e.w : e.y);
            // bubble insert into sorted (tv[0] best)
            if ((cv < tv[3]) || (cv == tv[3] && ci < ti[3])) { tv[3] = cv; ti[3] = ci; }
#pragma unroll
            for (int k = 3; k >= 1; --k) {
                const bool b = (tv[k] < tv[k-1]) || (tv[k] == tv[k-1] && ti[k] < ti[k-1]);
                if (b) { const float fv = tv[k]; tv[k] = tv[k-1]; tv[k-1] = fv;
                         const int   fi = ti[k]; ti[k] = ti[k-1]; ti[k-1] = fi; }
            }
        }
    }
    cand[row] = make_int4(ti[0], ti[1], ti[2], ti[3]);
}

// ------------------------------------------------ refine: exact fp32 dist for 4 candidates -> final idx
__launch_bounds__(256)
__global__ void k_refine(const _Float16* __restrict__ Xhi, const _Float16* __restrict__ Xlo,
                         const float* __restrict__ emb, const float* __restrict__ e2,
                         const int4* __restrict__ cand, int* __restrict__ idxOut,
                         int* __restrict__ counts) {
    const int n = blockIdx.x * 4 + (threadIdx.x >> 6);   // one wave per row
    const int lane = threadIdx.x & 63;
    const int d0 = lane * 4;

    const f16x4 xh = *(const f16x4*)(Xhi + (size_t)n * DDIM + d0);
    const f16x4 xl = *(const f16x4*)(Xlo + (size_t)n * DDIM + d0);
    const float x0 = (float)xh[0] + (float)xl[0];
    const float x1 = (float)xh[1] + (float)xl[1];
    const float x2 = (float)xh[2] + (float)xl[2];
    const float x3 = (float)xh[3] + (float)xl[3];

    const int4 c4 = cand[n];
    const int ci[4] = {c4.x, c4.y, c4.z, c4.w};
    float s[4];
#pragma unroll
    for (int cc = 0; cc < 4; ++cc) {
        const float4 ev = *(const float4*)(emb + (size_t)ci[cc] * DDIM + d0);
        s[cc] = x0 * ev.x + x1 * ev.y + x2 * ev.z + x3 * ev.w;
    }
#pragma unroll
    for (int off = 32; off >= 1; off >>= 1) {
#pragma unroll
        for (int cc = 0; cc < 4; ++cc) s[cc] += __shfl_down(s[cc], off);
    }
    if (lane == 0) {
        float bv = fmaf(-2.0f, s[0], e2[ci[0]]); int bi = ci[0];
#pragma unroll
        for (int cc = 1; cc < 4; ++cc) {
            const float dv = fmaf(-2.0f, s[cc], e2[ci[cc]]);
            if (dv < bv || (dv == bv && ci[cc] < bi)) { bv = dv; bi = ci[cc]; }
        }
        idxOut[n] = bi;
        atomicAdd(&counts[bi], 1);
    }
}

// ------------------------------------------------ quantized output + loss partial sums
__launch_bounds__(256)
__global__ void k_quant_loss(const float* __restrict__ inp, const float* __restrict__ emb,
                             const int* __restrict__ idx, float* __restrict__ outQ,
                             float* __restrict__ sumsq) {
    const int g  = blockIdx.x * 256 + threadIdx.x;
    const int e0 = g * 4;
    const int b  = e0 >> 20;
    const int rem = e0 & 1048575;
    const int d  = rem >> 12;
    const int hw = rem & (HWSZ - 1);
    const int nb = (b << 12) + hw;

    const int4  i4 = *(const int4*)(idx + nb);
    const float4 xv = *(const float4*)(inp + e0);
    const float q0 = emb[i4.x * DDIM + d];
    const float q1 = emb[i4.y * DDIM + d];
    const float q2 = emb[i4.z * DDIM + d];
    const float q3 = emb[i4.w * DDIM + d];
    outQ[e0 + 0] = q0; outQ[e0 + 1] = q1; outQ[e0 + 2] = q2; outQ[e0 + 3] = q3;

    const float d0 = q0 - xv.x, d1 = q1 - xv.y, d2 = q2 - xv.z, d3 = q3 - xv.w;
    float s = d0 * d0 + d1 * d1 + d2 * d2 + d3 * d3;
#pragma unroll
    for (int off = 32; off >= 1; off >>= 1) s += __shfl_down(s, off);
    __shared__ float wsum[4];
    const int lane = threadIdx.x & 63, wv = threadIdx.x >> 6;
    if (lane == 0) wsum[wv] = s;
    __syncthreads();
    if (threadIdx.x == 0) atomicAdd(sumsq, wsum[0] + wsum[1] + wsum[2] + wsum[3]);
}

// ------------------------------------------------ scalars
__launch_bounds__(256)
__global__ void k_finalize(const int* __restrict__ counts, const float* __restrict__ sumsq,
                           float* __restrict__ out) {
    __shared__ float red[256];
    const int t = threadIdx.x;
    float s = 0.0f;
    for (int k = t; k < KCODES; k += 256) {
        const float p = (float)counts[k] * (1.0f / 65536.0f);
        s += p * logf(p + 1e-10f);
    }
    red[t] = s;
    __syncthreads();
    for (int off = 128; off >= 1; off >>= 1) {
        if (t < off) red[t] += red[t + off];
        __syncthreads();
    }
    if (t == 0) {
        out[OUT_PERP] = expf(-red[0]);
        out[OUT_LOSS] = 0.25f * sumsq[0] * (1.0f / 16777216.0f);
    }
}

// ------------------------------------------------ one-hot encodings
__launch_bounds__(256)
__global__ void k_onehot(const int* __restrict__ idx, float2* __restrict__ enc) {
    const int n = blockIdx.x;
    const int id = idx[n];
    float2* rowp = enc + (size_t)n * 1024;
#pragma unroll
    for (int k = 0; k < 4; ++k) {
        const int col2 = k * 256 + threadIdx.x;
        const int cc = col2 * 2;
        float2 v;
        v.x = (cc == id) ? 1.0f : 0.0f;
        v.y = (cc + 1 == id) ? 1.0f : 0.0f;
        rowp[col2] = v;
    }
}

// ------------------------------------------------ launch
extern "C" void kernel_launch(void* const* d_in, const int* in_sizes, int n_in,
                              void* d_out, int out_size, void* d_ws, size_t ws_size,
                              hipStream_t stream) {
    const float* inp = (const float*)d_in[0];
    const float* emb = (const float*)d_in[1];
    float* out = (float*)d_out;

    int*       wsIdx  = (int*)d_ws;                 // 256 KB
    float4*    part   = (float4*)(out + SCR_PART);
    _Float16*  Xhi    = (_Float16*)(out + SCR_XHI);
    _Float16*  Xlo    = (_Float16*)(out + SCR_XLO);
    _Float16*  Ehi    = (_Float16*)(out + SCR_EHI);
    float*     e2     = out + SCR_E2;
    int*       counts = (int*)(out + SCR_CNT);
    float*     sumsq  = out + SCR_SUM;
    int4*      cand   = (int4*)(out + SCR_CAND);

    hipMemsetAsync((void*)counts, 0, (KCODES + 1) * sizeof(int), stream);

    k_split      <<<dim3(128, 8, 16), 256, 0, stream>>>(inp, Xhi, Xlo);
    k_esplit     <<<512,              256, 0, stream>>>(emb, Ehi);
    k_e2         <<<512,              256, 0, stream>>>(emb, e2);
    k_argmin_mfma<<<dim3(16, 512),    256, 0, stream>>>(Xhi, Ehi, e2, part);
    k_reduce     <<<256,              256, 0, stream>>>(part, cand);
    k_refine     <<<16384,            256, 0, stream>>>(Xhi, Xlo, emb, e2, cand, wsIdx, counts);
    k_quant_loss <<<16384,            256, 0, stream>>>(inp, emb, wsIdx, out + OUT_Q, sumsq);
    k_finalize   <<<1,                256, 0, stream>>>(counts, sumsq, out);
    k_onehot     <<<65536,            256, 0, stream>>>(wsIdx, (float2*)(out + OUT_ENC));
}

// Round 5
// 1052.467 us; speedup vs baseline: 1.6692x; 1.0755x over previous
//
#include <hip/hip_runtime.h>

// Problem: inputs [16,256,64,64] f32, embedding [2048,256] f32
#define NROWS   65536
#define KCODES  2048
#define DDIM    256
#define HWSZ    4096

// d_out float-element offsets (return order: loss, quantized, perplexity, encodings)
#define OUT_LOSS 0
#define OUT_Q    1
#define OUT_PERP 16777217
#define OUT_ENC  16777218

// Scratch carved from encodings region (k_onehot overwrites it last).
// SCR0 is 16B-aligned: (OUT_ENC+2)*4 % 16 == 0.
#define SCR0     (OUT_ENC + 2)
#define SCR_XHI  (SCR0)                  // _Float16 Xhi[65536*256]  = 8,388,608 floats
#define SCR_XLO  (SCR0 + 8388608)        // _Float16 Xlo[65536*256]
#define SCR_EHI  (SCR0 + 16777216)       // _Float16 Ehi[2048*256]   = 262,144 floats
#define SCR_E2   (SCR0 + 17039360)       // float e2[2048]
#define SCR_CNT  (SCR0 + 17041408)       // int counts[2048]
#define SCR_SUM  (SCR0 + 17043456)       // float sumsq[1] (+pad)
#define SCR_CAND (SCR0 + 17043460)       // int4 cand[65536], 16B-aligned

typedef _Float16 f16x8 __attribute__((ext_vector_type(8)));
typedef _Float16 f16x4 __attribute__((ext_vector_type(4)));
typedef float    f32x4 __attribute__((ext_vector_type(4)));

__device__ __forceinline__ void gld16(const void* g, void* l) {
    __builtin_amdgcn_global_load_lds((const __attribute__((address_space(1))) void*)g,
                                     (__attribute__((address_space(3))) void*)l, 16, 0, 0);
}

// ------------------------------------------------ split X: [B,D,HW] f32 -> Xhi/Xlo [N,D] f16
__launch_bounds__(256)
__global__ void k_split(const float* __restrict__ inp, _Float16* __restrict__ Xhi,
                        _Float16* __restrict__ Xlo) {
    __shared__ float tile[32][33];
    const int hw0 = blockIdx.x * 32, d0 = blockIdx.y * 32, b = blockIdx.z;
    const int tx = threadIdx.x & 31, ty = threadIdx.x >> 5;
#pragma unroll
    for (int i = 0; i < 32; i += 8)
        tile[ty + i][tx] = inp[b * 1048576 + (d0 + ty + i) * 4096 + hw0 + tx];
    __syncthreads();
#pragma unroll
    for (int i = 0; i < 32; i += 8) {
        const float x = tile[tx][ty + i];
        const _Float16 h = (_Float16)x;
        const _Float16 lo = (_Float16)(x - (float)h);
        const int n = b * 4096 + hw0 + ty + i;
        Xhi[n * DDIM + d0 + tx] = h;
        Xlo[n * DDIM + d0 + tx] = lo;
    }
}

// ------------------------------------------------ Ehi + ||e||^2 + zero counts/sumsq (one dispatch)
__launch_bounds__(256)
__global__ void k_e2split(const float* __restrict__ emb, _Float16* __restrict__ Ehi,
                          float* __restrict__ e2, int* __restrict__ counts,
                          float* __restrict__ sumsq) {
    const int wave = threadIdx.x >> 6;
    const int lane = threadIdx.x & 63;
    const int k = blockIdx.x * 4 + wave;          // 512 blocks
    const float4 v = *(const float4*)(emb + k * DDIM + lane * 4);
    f16x4 h;
    h[0] = (_Float16)v.x; h[1] = (_Float16)v.y; h[2] = (_Float16)v.z; h[3] = (_Float16)v.w;
    *(f16x4*)(Ehi + k * DDIM + lane * 4) = h;
    float s = v.x * v.x + v.y * v.y + v.z * v.z + v.w * v.w;
#pragma unroll
    for (int off = 32; off >= 1; off >>= 1) s += __shfl_down(s, off);
    if (lane == 0) e2[k] = s;
    if (blockIdx.x < 8) counts[blockIdx.x * 256 + threadIdx.x] = 0;
    if (blockIdx.x == 8 && threadIdx.x == 0) sumsq[0] = 0.0f;
}

// top-2 pair merge with idx tie-break (lower idx wins)
#define MERGE2(m1,i1,m2,i2,n1,j1,n2,j2)                                   \
    {                                                                     \
        const bool w_ = ((n1) < (m1)) || ((n1) == (m1) && (j1) < (i1));   \
        const float w1_ = w_ ? (n1) : (m1); const int wi_ = w_ ? (j1) : (i1); \
        const float l1_ = w_ ? (m1) : (n1); const int li_ = w_ ? (i1) : (j1); \
        const float c2_ = w_ ? (n2) : (m2); const int ci_ = w_ ? (j2) : (i2); \
        const bool s_ = ((c2_) < (l1_)) || ((c2_) == (l1_) && (ci_) < (li_)); \
        (m1) = w1_; (i1) = wi_;                                           \
        (m2) = s_ ? c2_ : l1_; (i2) = s_ ? ci_ : li_;                     \
    }

// ------------------------------------------------ stage-1: one block = 128 rows x ALL 2048 cols.
// Approx dist = e2 - 2*(xhi.ehi). Running per-lane top-2 (branch-free, no shuffles in the
// ct loop); single cross-lane merge at the end -> 4 candidates/row. No part/reduce pass.
__launch_bounds__(256, 2)
__global__ void k_topk(const _Float16* __restrict__ Xhi, const _Float16* __restrict__ Ehi,
                       const float* __restrict__ e2, int4* __restrict__ cand) {
    __shared__ _Float16 Ah[128 * 64];   // 16 KB (merge scratch aliased post-loop)
    __shared__ _Float16 Bh[128 * 64];   // 16 KB

    const int rb = blockIdx.x;            // 512 row blocks of 128 rows
    const int n0 = rb * 128;
    const int tid = threadIdx.x;
    const int w = tid >> 6, lane = tid & 63;
    const int wr = (w >> 1) * 64, wc = (w & 1) * 64;   // wave quadrant
    const int lq = lane >> 4, lm = lane & 15;
    const int r = lane >> 3, c = lane & 7;
    const int gch = c ^ r;                // XOR-swizzled source chunk

    float V1[4][4], V2[4][4]; int I1[4][4], I2[4][4];
#pragma unroll
    for (int i = 0; i < 4; ++i)
#pragma unroll
        for (int rr = 0; rr < 4; ++rr) {
            V1[i][rr] = 3.402823466e38f; V2[i][rr] = 3.402823466e38f;
            I1[i][rr] = 0x7fffffff;      I2[i][rr] = 0x7fffffff;
        }

#pragma unroll 1
    for (int ct = 0; ct < 16; ++ct) {
        const int c0 = ct * 128;
        f32x4 acc[4][4];
#pragma unroll
        for (int i = 0; i < 4; ++i)
#pragma unroll
            for (int j = 0; j < 4; ++j) acc[i][j] = (f32x4)(0.0f);

#pragma unroll 1
        for (int kt = 0; kt < 4; ++kt) {
            const int d0 = kt * 64;
            __syncthreads();
#pragma unroll
            for (int i = 0; i < 4; ++i) {
                const int Row = i * 32 + w * 8 + r;
                gld16(Xhi + (size_t)(n0 + Row) * DDIM + d0 + gch * 8, &Ah[(i * 32 + w * 8) * 64]);
                gld16(Ehi + (size_t)(c0 + Row) * DDIM + d0 + gch * 8, &Bh[(i * 32 + w * 8) * 64]);
            }
            __syncthreads();
#pragma unroll
            for (int s = 0; s < 2; ++s) {
                const int wch = s * 4 + lq;
                f16x8 af[4], bf[4];
#pragma unroll
                for (int t = 0; t < 4; ++t) {
                    const int Ra = wr + t * 16 + lm;
                    const int Rb = wc + t * 16 + lm;
                    af[t] = *(const f16x8*)&Ah[Ra * 64 + ((wch ^ (Ra & 7)) * 8)];
                    bf[t] = *(const f16x8*)&Bh[Rb * 64 + ((wch ^ (Rb & 7)) * 8)];
                }
#pragma unroll
                for (int i = 0; i < 4; ++i)
#pragma unroll
                    for (int j = 0; j < 4; ++j)
                        acc[i][j] = __builtin_amdgcn_mfma_f32_16x16x32_f16(af[i], bf[j], acc[i][j], 0, 0, 0);
            }
        }

        // per-ct epilogue: branch-free running top-2 update (idx ascending scan ->
        // strict < implements lowest-idx tie-break). C layout: col=lm, row=lq*4+reg.
        float e2v[4];
#pragma unroll
        for (int j = 0; j < 4; ++j) e2v[j] = e2[c0 + wc + j * 16 + lm];
#pragma unroll
        for (int i = 0; i < 4; ++i)
#pragma unroll
            for (int j = 0; j < 4; ++j) {
                const int idx = c0 + wc + j * 16 + lm;
#pragma unroll
                for (int rr = 0; rr < 4; ++rr) {
                    const float dist = fmaf(-2.0f, acc[i][j][rr], e2v[j]);
                    const bool b1 = dist < V1[i][rr];
                    const bool b2 = dist < V2[i][rr];
                    V2[i][rr] = b1 ? V1[i][rr] : (b2 ? dist : V2[i][rr]);
                    I2[i][rr] = b1 ? I1[i][rr] : (b2 ? idx  : I2[i][rr]);
                    V1[i][rr] = b1 ? dist : V1[i][rr];
                    I1[i][rr] = b1 ? idx  : I1[i][rr];
                }
            }
    }

    // once-per-block: merge 16 lm lanes -> per-wave (col-half) exact top-2 per row
    __syncthreads();                       // LDS frag reads done -> safe to alias
    float4* red = (float4*)Ah;             // [128][2]
#pragma unroll
    for (int i = 0; i < 4; ++i)
#pragma unroll
        for (int rr = 0; rr < 4; ++rr) {
            float m1 = V1[i][rr]; int i1 = I1[i][rr];
            float m2 = V2[i][rr]; int i2 = I2[i][rr];
#pragma unroll
            for (int off = 1; off < 16; off <<= 1) {
                const float n1 = __shfl_xor(m1, off); const int j1 = __shfl_xor(i1, off);
                const float n2 = __shfl_xor(m2, off); const int j2 = __shfl_xor(i2, off);
                MERGE2(m1, i1, m2, i2, n1, j1, n2, j2);
            }
            if (lm == 0) {
                const int row = wr + i * 16 + lq * 4 + rr;
                red[row * 2 + (w & 1)] = make_float4(m1, __int_as_float(i1),
                                                     m2, __int_as_float(i2));
            }
        }
    __syncthreads();
    if (tid < 128) {
        const float4 A = red[tid * 2];
        const float4 B = red[tid * 2 + 1];
        // union of the two col-half top-2s: contains exact approx-top-2 + 2 extras
        cand[n0 + tid] = make_int4(__float_as_int(A.y), __float_as_int(A.w),
                                   __float_as_int(B.y), __float_as_int(B.w));
    }
}

// ------------------------------------------------ refine: exact fp32 dist for 4 candidates -> final idx
__launch_bounds__(256)
__global__ void k_refine(const _Float16* __restrict__ Xhi, const _Float16* __restrict__ Xlo,
                         const float* __restrict__ emb, const float* __restrict__ e2,
                         const int4* __restrict__ cand, int* __restrict__ idxOut,
                         int* __restrict__ counts) {
    const int n = blockIdx.x * 4 + (threadIdx.x >> 6);   // one wave per row
    const int lane = threadIdx.x & 63;
    const int d0 = lane * 4;

    const f16x4 xh = *(const f16x4*)(Xhi + (size_t)n * DDIM + d0);
    const f16x4 xl = *(const f16x4*)(Xlo + (size_t)n * DDIM + d0);
    const float x0 = (float)xh[0] + (float)xl[0];
    const float x1 = (float)xh[1] + (float)xl[1];
    const float x2 = (float)xh[2] + (float)xl[2];
    const float x3 = (float)xh[3] + (float)xl[3];

    const int4 c4 = cand[n];
    const int ci[4] = {c4.x, c4.y, c4.z, c4.w};
    float s[4];
#pragma unroll
    for (int cc = 0; cc < 4; ++cc) {
        const float4 ev = *(const float4*)(emb + (size_t)ci[cc] * DDIM + d0);
        s[cc] = x0 * ev.x + x1 * ev.y + x2 * ev.z + x3 * ev.w;
    }
#pragma unroll
    for (int off = 32; off >= 1; off >>= 1) {
#pragma unroll
        for (int cc = 0; cc < 4; ++cc) s[cc] += __shfl_down(s[cc], off);
    }
    if (lane == 0) {
        float bv = fmaf(-2.0f, s[0], e2[ci[0]]); int bi = ci[0];
#pragma unroll
        for (int cc = 1; cc < 4; ++cc) {
            const float dv = fmaf(-2.0f, s[cc], e2[ci[cc]]);
            if (dv < bv || (dv == bv && ci[cc] < bi)) { bv = dv; bi = ci[cc]; }
        }
        idxOut[n] = bi;
        atomicAdd(&counts[bi], 1);
    }
}

// ------------------------------------------------ quantized output + loss partial sums
__launch_bounds__(256)
__global__ void k_quant_loss(const float* __restrict__ inp, const float* __restrict__ emb,
                             const int* __restrict__ idx, float* __restrict__ outQ,
                             float* __restrict__ sumsq) {
    const int g  = blockIdx.x * 256 + threadIdx.x;
    const int e0 = g * 4;
    const int b  = e0 >> 20;
    const int rem = e0 & 1048575;
    const int d  = rem >> 12;
    const int hw = rem & (HWSZ - 1);
    const int nb = (b << 12) + hw;

    const int4  i4 = *(const int4*)(idx + nb);
    const float4 xv = *(const float4*)(inp + e0);
    const float q0 = emb[i4.x * DDIM + d];
    const float q1 = emb[i4.y * DDIM + d];
    const float q2 = emb[i4.z * DDIM + d];
    const float q3 = emb[i4.w * DDIM + d];
    outQ[e0 + 0] = q0; outQ[e0 + 1] = q1; outQ[e0 + 2] = q2; outQ[e0 + 3] = q3;

    const float d0 = q0 - xv.x, d1 = q1 - xv.y, d2 = q2 - xv.z, d3 = q3 - xv.w;
    float s = d0 * d0 + d1 * d1 + d2 * d2 + d3 * d3;
#pragma unroll
    for (int off = 32; off >= 1; off >>= 1) s += __shfl_down(s, off);
    __shared__ float wsum[4];
    const int lane = threadIdx.x & 63, wv = threadIdx.x >> 6;
    if (lane == 0) wsum[wv] = s;
    __syncthreads();
    if (threadIdx.x == 0) atomicAdd(sumsq, wsum[0] + wsum[1] + wsum[2] + wsum[3]);
}

// ------------------------------------------------ scalars
__launch_bounds__(256)
__global__ void k_finalize(const int* __restrict__ counts, const float* __restrict__ sumsq,
                           float* __restrict__ out) {
    __shared__ float red[256];
    const int t = threadIdx.x;
    float s = 0.0f;
    for (int k = t; k < KCODES; k += 256) {
        const float p = (float)counts[k] * (1.0f / 65536.0f);
        s += p * logf(p + 1e-10f);
    }
    red[t] = s;
    __syncthreads();
    for (int off = 128; off >= 1; off >>= 1) {
        if (t < off) red[t] += red[t + off];
        __syncthreads();
    }
    if (t == 0) {
        out[OUT_PERP] = expf(-red[0]);
        out[OUT_LOSS] = 0.25f * sumsq[0] * (1.0f / 16777216.0f);
    }
}

// ------------------------------------------------ one-hot encodings
__launch_bounds__(256)
__global__ void k_onehot(const int* __restrict__ idx, float2* __restrict__ enc) {
    const int n = blockIdx.x;
    const int id = idx[n];
    float2* rowp = enc + (size_t)n * 1024;
#pragma unroll
    for (int k = 0; k < 4; ++k) {
        const int col2 = k * 256 + threadIdx.x;
        const int cc = col2 * 2;
        float2 v;
        v.x = (cc == id) ? 1.0f : 0.0f;
        v.y = (cc + 1 == id) ? 1.0f : 0.0f;
        rowp[col2] = v;
    }
}

// ------------------------------------------------ launch
extern "C" void kernel_launch(void* const* d_in, const int* in_sizes, int n_in,
                              void* d_out, int out_size, void* d_ws, size_t ws_size,
                              hipStream_t stream) {
    const float* inp = (const float*)d_in[0];
    const float* emb = (const float*)d_in[1];
    float* out = (float*)d_out;

    int*       wsIdx  = (int*)d_ws;                 // 256 KB
    _Float16*  Xhi    = (_Float16*)(out + SCR_XHI);
    _Float16*  Xlo    = (_Float16*)(out + SCR_XLO);
    _Float16*  Ehi    = (_Float16*)(out + SCR_EHI);
    float*     e2     = out + SCR_E2;
    int*       counts = (int*)(out + SCR_CNT);
    float*     sumsq  = out + SCR_SUM;
    int4*      cand   = (int4*)(out + SCR_CAND);

    k_split      <<<dim3(128, 8, 16), 256, 0, stream>>>(inp, Xhi, Xlo);
    k_e2split    <<<512,              256, 0, stream>>>(emb, Ehi, e2, counts, sumsq);
    k_topk       <<<512,              256, 0, stream>>>(Xhi, Ehi, e2, cand);
    k_refine     <<<16384,            256, 0, stream>>>(Xhi, Xlo, emb, e2, cand, wsIdx, counts);
    k_quant_loss <<<16384,            256, 0, stream>>>(inp, emb, wsIdx, out + OUT_Q, sumsq);
    k_finalize   <<<1,                256, 0, stream>>>(counts, sumsq, out);
    k_onehot     <<<65536,            256, 0, stream>>>(wsIdx, (float2*)(out + OUT_ENC));
}

// Round 6
// 887.683 us; speedup vs baseline: 1.9790x; 1.1856x over previous
//
#include <hip/hip_runtime.h>

// Problem: inputs [16,256,64,64] f32, embedding [2048,256] f32
#define NROWS   65536
#define KCODES  2048
#define DDIM    256
#define HWSZ    4096

// d_out float-element offsets (return order: loss, quantized, perplexity, encodings)
#define OUT_LOSS 0
#define OUT_Q    1
#define OUT_PERP 16777217
#define OUT_ENC  16777218

// Scratch in the encodings region: consumed ONLY by k_topk (which completes before
// k_tail's enc writes begin -> no race). SCR0 is 16B-aligned.
#define SCR0     (OUT_ENC + 2)
#define SCR_XHI  (SCR0)                  // _Float16 Xhi[65536*256] = 8,388,608 floats
#define SCR_EHI  (SCR0 + 8388608)        // _Float16 Ehi[2048*256]

// d_ws byte offsets (ws poison fill is ~2.4 GB -> ws is large; we use ~1.04 MiB).
// These MUST be outside the enc region: k_tail reads/atomics them while writing enc.
#define WS_CAND 0                         // int4 cand[65536]  = 1 MiB
#define WS_E2   1048576                   // float e2[2048]
#define WS_CNT  1056768                   // int counts[2048]
#define WS_SUM  1064960                   // float sumsq[1]

typedef _Float16 f16x8 __attribute__((ext_vector_type(8)));
typedef _Float16 f16x4 __attribute__((ext_vector_type(4)));
typedef float    f32x4 __attribute__((ext_vector_type(4)));

__device__ __forceinline__ void gld16(const void* g, void* l) {
    __builtin_amdgcn_global_load_lds((const __attribute__((address_space(1))) void*)g,
                                     (__attribute__((address_space(3))) void*)l, 16, 0, 0);
}

// ------------------------------------------------ split X: [B,D,HW] f32 -> Xhi [N,D] f16 (hi plane only)
__launch_bounds__(256)
__global__ void k_split(const float* __restrict__ inp, _Float16* __restrict__ Xhi) {
    __shared__ float tile[32][33];
    const int hw0 = blockIdx.x * 32, d0 = blockIdx.y * 32, b = blockIdx.z;
    const int tx = threadIdx.x & 31, ty = threadIdx.x >> 5;
#pragma unroll
    for (int i = 0; i < 32; i += 8)
        tile[ty + i][tx] = inp[b * 1048576 + (d0 + ty + i) * 4096 + hw0 + tx];
    __syncthreads();
#pragma unroll
    for (int i = 0; i < 32; i += 8) {
        const int n = b * 4096 + hw0 + ty + i;
        Xhi[n * DDIM + d0 + tx] = (_Float16)tile[tx][ty + i];
    }
}

// ------------------------------------------------ Ehi + ||e||^2 + zero counts/sumsq (one dispatch)
__launch_bounds__(256)
__global__ void k_e2split(const float* __restrict__ emb, _Float16* __restrict__ Ehi,
                          float* __restrict__ e2, int* __restrict__ counts,
                          float* __restrict__ sumsq) {
    const int wave = threadIdx.x >> 6;
    const int lane = threadIdx.x & 63;
    const int k = blockIdx.x * 4 + wave;          // 512 blocks
    const float4 v = *(const float4*)(emb + k * DDIM + lane * 4);
    f16x4 h;
    h[0] = (_Float16)v.x; h[1] = (_Float16)v.y; h[2] = (_Float16)v.z; h[3] = (_Float16)v.w;
    *(f16x4*)(Ehi + k * DDIM + lane * 4) = h;
    float s = v.x * v.x + v.y * v.y + v.z * v.z + v.w * v.w;
#pragma unroll
    for (int off = 32; off >= 1; off >>= 1) s += __shfl_down(s, off);
    if (lane == 0) e2[k] = s;
    if (blockIdx.x < 8) counts[blockIdx.x * 256 + threadIdx.x] = 0;
    if (blockIdx.x == 8 && threadIdx.x == 0) sumsq[0] = 0.0f;
}

// top-2 pair merge with idx tie-break (lower idx wins)
#define MERGE2(m1,i1,m2,i2,n1,j1,n2,j2)                                   \
    {                                                                     \
        const bool w_ = ((n1) < (m1)) || ((n1) == (m1) && (j1) < (i1));   \
        const float w1_ = w_ ? (n1) : (m1); const int wi_ = w_ ? (j1) : (i1); \
        const float l1_ = w_ ? (m1) : (n1); const int li_ = w_ ? (i1) : (j1); \
        const float c2_ = w_ ? (n2) : (m2); const int ci_ = w_ ? (j2) : (i2); \
        const bool s_ = ((c2_) < (l1_)) || ((c2_) == (l1_) && (ci_) < (li_)); \
        (m1) = w1_; (i1) = wi_;                                           \
        (m2) = s_ ? c2_ : l1_; (i2) = s_ ? ci_ : li_;                     \
    }

// ------------------------------------------------ stage-1: one block = 128 rows x ALL 2048 cols.
// Approx dist = e2 - 2*(xhi.ehi). Per-lane running top-2; one cross-lane merge at the end
// -> 4 candidates/row (union of two col-half top-2s; contains global approx-top-2).
__launch_bounds__(256, 2)
__global__ void k_topk(const _Float16* __restrict__ Xhi, const _Float16* __restrict__ Ehi,
                       const float* __restrict__ e2, int4* __restrict__ cand) {
    __shared__ _Float16 Ah[128 * 64];   // 16 KB (merge scratch aliased post-loop)
    __shared__ _Float16 Bh[128 * 64];   // 16 KB

    const int rb = blockIdx.x;            // 512 row blocks of 128 rows
    const int n0 = rb * 128;
    const int tid = threadIdx.x;
    const int w = tid >> 6, lane = tid & 63;
    const int wr = (w >> 1) * 64, wc = (w & 1) * 64;   // wave quadrant
    const int lq = lane >> 4, lm = lane & 15;
    const int r = lane >> 3, c = lane & 7;
    const int gch = c ^ r;                // XOR-swizzled source chunk

    float V1[4][4], V2[4][4]; int I1[4][4], I2[4][4];
#pragma unroll
    for (int i = 0; i < 4; ++i)
#pragma unroll
        for (int rr = 0; rr < 4; ++rr) {
            V1[i][rr] = 3.402823466e38f; V2[i][rr] = 3.402823466e38f;
            I1[i][rr] = 0x7fffffff;      I2[i][rr] = 0x7fffffff;
        }

#pragma unroll 1
    for (int ct = 0; ct < 16; ++ct) {
        const int c0 = ct * 128;
        f32x4 acc[4][4];
#pragma unroll
        for (int i = 0; i < 4; ++i)
#pragma unroll
            for (int j = 0; j < 4; ++j) acc[i][j] = (f32x4)(0.0f);

#pragma unroll 1
        for (int kt = 0; kt < 4; ++kt) {
            const int d0 = kt * 64;
            __syncthreads();
#pragma unroll
            for (int i = 0; i < 4; ++i) {
                const int Row = i * 32 + w * 8 + r;
                gld16(Xhi + (size_t)(n0 + Row) * DDIM + d0 + gch * 8, &Ah[(i * 32 + w * 8) * 64]);
                gld16(Ehi + (size_t)(c0 + Row) * DDIM + d0 + gch * 8, &Bh[(i * 32 + w * 8) * 64]);
            }
            __syncthreads();
#pragma unroll
            for (int s = 0; s < 2; ++s) {
                const int wch = s * 4 + lq;
                f16x8 af[4], bf[4];
#pragma unroll
                for (int t = 0; t < 4; ++t) {
                    const int Ra = wr + t * 16 + lm;
                    const int Rb = wc + t * 16 + lm;
                    af[t] = *(const f16x8*)&Ah[Ra * 64 + ((wch ^ (Ra & 7)) * 8)];
                    bf[t] = *(const f16x8*)&Bh[Rb * 64 + ((wch ^ (Rb & 7)) * 8)];
                }
#pragma unroll
                for (int i = 0; i < 4; ++i)
#pragma unroll
                    for (int j = 0; j < 4; ++j)
                        acc[i][j] = __builtin_amdgcn_mfma_f32_16x16x32_f16(af[i], bf[j], acc[i][j], 0, 0, 0);
            }
        }

        // per-ct epilogue: branch-free running top-2. C layout: col=lm, row=lq*4+reg.
        float e2v[4];
#pragma unroll
        for (int j = 0; j < 4; ++j) e2v[j] = e2[c0 + wc + j * 16 + lm];
#pragma unroll
        for (int i = 0; i < 4; ++i)
#pragma unroll
            for (int j = 0; j < 4; ++j) {
                const int idx = c0 + wc + j * 16 + lm;
#pragma unroll
                for (int rr = 0; rr < 4; ++rr) {
                    const float dist = fmaf(-2.0f, acc[i][j][rr], e2v[j]);
                    const bool b1 = dist < V1[i][rr];
                    const bool b2 = dist < V2[i][rr];
                    V2[i][rr] = b1 ? V1[i][rr] : (b2 ? dist : V2[i][rr]);
                    I2[i][rr] = b1 ? I1[i][rr] : (b2 ? idx  : I2[i][rr]);
                    V1[i][rr] = b1 ? dist : V1[i][rr];
                    I1[i][rr] = b1 ? idx  : I1[i][rr];
                }
            }
    }

    __syncthreads();                       // LDS frag reads done -> safe to alias
    float4* red = (float4*)Ah;             // [128][2]
#pragma unroll
    for (int i = 0; i < 4; ++i)
#pragma unroll
        for (int rr = 0; rr < 4; ++rr) {
            float m1 = V1[i][rr]; int i1 = I1[i][rr];
            float m2 = V2[i][rr]; int i2 = I2[i][rr];
#pragma unroll
            for (int off = 1; off < 16; off <<= 1) {
                const float n1 = __shfl_xor(m1, off); const int j1 = __shfl_xor(i1, off);
                const float n2 = __shfl_xor(m2, off); const int j2 = __shfl_xor(i2, off);
                MERGE2(m1, i1, m2, i2, n1, j1, n2, j2);
            }
            if (lm == 0) {
                const int row = wr + i * 16 + lq * 4 + rr;
                red[row * 2 + (w & 1)] = make_float4(m1, __int_as_float(i1),
                                                     m2, __int_as_float(i2));
            }
        }
    __syncthreads();
    if (tid < 128) {
        const float4 A = red[tid * 2];
        const float4 B = red[tid * 2 + 1];
        cand[n0 + tid] = make_int4(__float_as_int(A.y), __float_as_int(A.w),
                                   __float_as_int(B.y), __float_as_int(B.w));
    }
}

// ------------------------------------------------ fused tail: exact refine + quantized + loss
// + counts + one-hot encodings. Block = 64 rows (b, hw0..hw0+63); wave w owns d-range
// [w*64, w*64+64). Lane l <-> row hw0+l (coalesced 256 B/inst on inp/outQ).
__launch_bounds__(256)
__global__ void k_tail(const float* __restrict__ inp, const float* __restrict__ emb,
                       const float* __restrict__ e2, const int4* __restrict__ cand,
                       int* __restrict__ counts, float* __restrict__ sumsq,
                       float* __restrict__ outQ, float2* __restrict__ enc) {
    __shared__ float part[4][64][5];   // [wave][row][s0..s3, x2]
    __shared__ int   idxs[64];

    const int blk = blockIdx.x;            // 1024 blocks
    const int b   = blk >> 6;
    const int hw0 = (blk & 63) << 6;
    const int w = threadIdx.x >> 6, lane = threadIdx.x & 63;
    const int n0 = (b << 12) + hw0;

    // ---- phase 1a: partial dots (exact fp32 x) for the 4 candidates + ||x||^2
    const int4 c4 = cand[n0 + lane];
    const float* xp  = inp + (size_t)b * 1048576 + (size_t)(w * 64) * 4096 + hw0 + lane;
    const float* ep0 = emb + (size_t)c4.x * DDIM + w * 64;
    const float* ep1 = emb + (size_t)c4.y * DDIM + w * 64;
    const float* ep2 = emb + (size_t)c4.z * DDIM + w * 64;
    const float* ep3 = emb + (size_t)c4.w * DDIM + w * 64;
    float s0 = 0.f, s1 = 0.f, s2 = 0.f, s3 = 0.f, x2 = 0.f;
#pragma unroll 8
    for (int dd = 0; dd < 64; ++dd) {
        const float xv = xp[(size_t)dd * 4096];
        s0 = fmaf(xv, ep0[dd], s0);
        s1 = fmaf(xv, ep1[dd], s1);
        s2 = fmaf(xv, ep2[dd], s2);
        s3 = fmaf(xv, ep3[dd], s3);
        x2 = fmaf(xv, xv, x2);
    }
    part[w][lane][0] = s0; part[w][lane][1] = s1; part[w][lane][2] = s2;
    part[w][lane][3] = s3; part[w][lane][4] = x2;
    __syncthreads();

    // ---- phase 1b: wave 0 reduces 4 wave-partials per row, picks best, loss + counts
    if (threadIdx.x < 64) {
        const int rr = threadIdx.x;
        float S[5];
#pragma unroll
        for (int k = 0; k < 5; ++k)
            S[k] = part[0][rr][k] + part[1][rr][k] + part[2][rr][k] + part[3][rr][k];
        const int4 cc = cand[n0 + rr];
        const int cid[4] = {cc.x, cc.y, cc.z, cc.w};
        float bv = 3.402823466e38f; int bi = 0; float sb = 0.f, eb = 0.f;
#pragma unroll
        for (int k = 0; k < 4; ++k) {
            const float ev = e2[cid[k]];
            const float dv = fmaf(-2.0f, S[k], ev);
            if (dv < bv || (dv == bv && cid[k] < bi)) { bv = dv; bi = cid[k]; sb = S[k]; eb = ev; }
        }
        idxs[rr] = bi;
        atomicAdd(&counts[bi], 1);
        // ||x - q||^2 = ||x||^2 - 2 x.q + ||q||^2
        float lr = S[4] - 2.0f * sb + eb;
#pragma unroll
        for (int off = 32; off >= 1; off >>= 1) lr += __shfl_down(lr, off);
        if (rr == 0) atomicAdd(sumsq, lr);
    }
    __syncthreads();

    // ---- phase 2: quantized output (gather emb[idx], coalesced 256 B stores)
    const int myidx = idxs[lane];
    const float* qp = emb + (size_t)myidx * DDIM + w * 64;
    float* op = outQ + (size_t)b * 1048576 + (size_t)(w * 64) * 4096 + hw0 + lane;
#pragma unroll 8
    for (int dd = 0; dd < 64; ++dd) op[(size_t)dd * 4096] = qp[dd];

    // ---- phase 3: one-hot encodings (64 rows x 8 KB)
    float2* erow = enc + (size_t)n0 * 1024;
#pragma unroll 1
    for (int rr = 0; rr < 64; ++rr) {
        const int id = idxs[rr];
        float2* rp = erow + (size_t)rr * 1024;
#pragma unroll
        for (int k = 0; k < 4; ++k) {
            const int c2 = k * 256 + threadIdx.x;
            const int ccc = c2 * 2;
            float2 v;
            v.x = (ccc == id) ? 1.0f : 0.0f;
            v.y = (ccc + 1 == id) ? 1.0f : 0.0f;
            rp[c2] = v;
        }
    }
}

// ------------------------------------------------ scalars
__launch_bounds__(256)
__global__ void k_finalize(const int* __restrict__ counts, const float* __restrict__ sumsq,
                           float* __restrict__ out) {
    __shared__ float red[256];
    const int t = threadIdx.x;
    float s = 0.0f;
    for (int k = t; k < KCODES; k += 256) {
        const float p = (float)counts[k] * (1.0f / 65536.0f);
        s += p * logf(p + 1e-10f);
    }
    red[t] = s;
    __syncthreads();
    for (int off = 128; off >= 1; off >>= 1) {
        if (t < off) red[t] += red[t + off];
        __syncthreads();
    }
    if (t == 0) {
        out[OUT_PERP] = expf(-red[0]);
        out[OUT_LOSS] = 0.25f * sumsq[0] * (1.0f / 16777216.0f);
    }
}

// ------------------------------------------------ launch
extern "C" void kernel_launch(void* const* d_in, const int* in_sizes, int n_in,
                              void* d_out, int out_size, void* d_ws, size_t ws_size,
                              hipStream_t stream) {
    const float* inp = (const float*)d_in[0];
    const float* emb = (const float*)d_in[1];
    float* out = (float*)d_out;
    char* wsb  = (char*)d_ws;

    _Float16* Xhi    = (_Float16*)(out + SCR_XHI);
    _Float16* Ehi    = (_Float16*)(out + SCR_EHI);
    int4*     cand   = (int4*)(wsb + WS_CAND);
    float*    e2     = (float*)(wsb + WS_E2);
    int*      counts = (int*)(wsb + WS_CNT);
    float*    sumsq  = (float*)(wsb + WS_SUM);

    k_split   <<<dim3(128, 8, 16), 256, 0, stream>>>(inp, Xhi);
    k_e2split <<<512,              256, 0, stream>>>(emb, Ehi, e2, counts, sumsq);
    k_topk    <<<512,              256, 0, stream>>>(Xhi, Ehi, e2, cand);
    k_tail    <<<1024,             256, 0, stream>>>(inp, emb, e2, cand, counts, sumsq,
                                                     out + OUT_Q, (float2*)(out + OUT_ENC));
    k_finalize<<<1,                256, 0, stream>>>(counts, sumsq, out);
}